// Round 5
// baseline (223.147 us; speedup 1.0000x reference)
//
#include <hip/hip_runtime.h>
#include <hip/hip_bf16.h>
#include <cstddef>

// G=1024 x 64 nodes, V=32, H=128, DIN=128, DOUT=10, E=1048576.
// R5 = R4 with (a) ALL LDS row strides made 16-byte multiples (R4's 68/132/36
// element strides produced misaligned ds_read_b128 -> memory fault / abort),
// (b) S = vemb @ aff_W2^T computed by MFMA in its own kernel (prepS) instead
// of R4's scalar-LDS dot products, (c) sGfp aliased onto the dead bounce
// region so 4 blocks/CU still holds (40,704 B <= 40,960 B).

#define EDGES 1048576
#define TS 72    // transposed [feat][node] stride (bf16): 144 B, 16-B multiple
#define AS 64    // adjacency / ewn^T stride: 128 B, 16-B multiple
#define VS 136   // 32-row row-major stride: 272 B, 16-B multiple
#define BS 40    // per-wave bounce slab stride: 80 B, 16-B multiple

typedef __attribute__((ext_vector_type(8))) short short8;
typedef __attribute__((ext_vector_type(4))) float f32x4;
typedef __hip_bfloat16 bf;
struct __align__(8) bf4 { bf v[4]; };

// fragment-linear weight layout: off(n,k) = ((n>>4)*4 + (k>>5))*512 + (n&15)*32 + (k&31)
__device__ __forceinline__ int foff(int nt, int ks, int l15, int kofs) {
    return (nt * 4 + ks) * 512 + l15 * 32 + kofs;
}

// ---- conv: weight fold + fragment-linear conversions + bfold + Cnt zero ----
// gWb: [0]=W_emb@W_gcn (fold) [1]=aff_W1^T [2]=vn_W1^T [3]=vn_W2^T ; gW2f = aff_W2 straight
__global__ __launch_bounds__(256) void conv(
    const float* __restrict__ W_emb, const float* __restrict__ W_gcn,
    const float* __restrict__ b_emb, const float* __restrict__ aff_W1,
    const float* __restrict__ vn_W1, const float* __restrict__ vn_W2,
    const float* __restrict__ aff_W2,
    bf* __restrict__ gWb, bf* __restrict__ gW2f, float* __restrict__ bfold,
    unsigned* __restrict__ Cnt)
{
    int b = blockIdx.x, t = threadIdx.x;
    if (b < 4) {                       // fold: Wfold[k][j] = sum_m W_emb[k][m]*W_gcn[m][j]
        __shared__ float we[32 * 128];
        int k0 = b * 32;
        for (int i = t; i < 4096; i += 256) we[i] = W_emb[k0 * 128 + i];
        __syncthreads();
        int kk = t >> 3, jg = t & 7;
        float acc[16] = {};
        for (int m = 0; m < 128; ++m) {
            float a = we[kk * 128 + m];
            const float4* wr = (const float4*)(W_gcn + m * 128 + jg * 16);
            float4 w0 = wr[0], w1 = wr[1], w2 = wr[2], w3 = wr[3];
            acc[0]  += a * w0.x; acc[1]  += a * w0.y; acc[2]  += a * w0.z; acc[3]  += a * w0.w;
            acc[4]  += a * w1.x; acc[5]  += a * w1.y; acc[6]  += a * w1.z; acc[7]  += a * w1.w;
            acc[8]  += a * w2.x; acc[9]  += a * w2.y; acc[10] += a * w2.z; acc[11] += a * w2.w;
            acc[12] += a * w3.x; acc[13] += a * w3.y; acc[14] += a * w3.z; acc[15] += a * w3.w;
        }
        int k = k0 + kk;
        for (int jj = 0; jj < 16; ++jj) {
            int j = jg * 16 + jj;
            int off = ((j >> 4) * 4 + (k >> 5)) * 512 + (j & 15) * 32 + (k & 31);
            gWb[off] = __float2bfloat16(acc[jj]);
        }
    } else if (b == 4) {
        if (t < 128) {
            float acc = 0.f;
            for (int m = 0; m < 128; ++m) acc += b_emb[m] * W_gcn[m * 128 + t];
            bfold[t] = acc;
        }
        for (int i = t; i < 1024; i += 256) Cnt[i] = 0u;
    } else if (b < 8) {                // transposed: B[n][k] = W[k][n]
        const float* src = (b == 5) ? aff_W1 : (b == 6) ? vn_W1 : vn_W2;
        bf* dst = gWb + (size_t)(b - 4) * 16384;
        for (int i = t; i < 16384; i += 256) {
            int n = i >> 7, k = i & 127;
            int off = ((n >> 4) * 4 + (k >> 5)) * 512 + (n & 15) * 32 + (k & 31);
            dst[off] = __float2bfloat16(src[k * 128 + n]);
        }
    } else {                           // aff_W2 straight: B[n=j][k=o] = W[j][o]
        for (int i = t; i < 16384; i += 256) {
            int n = i >> 7, k = i & 127;
            int off = ((n >> 4) * 4 + (k >> 5)) * 512 + (n & 15) * 32 + (k & 31);
            gW2f[off] = __float2bfloat16(aff_W2[n * 128 + k]);
        }
    }
}

// ------------- scat: hist -> reserve(global atomic) -> rank+store -------------
__global__ __launch_bounds__(256) void scat(const int* __restrict__ ei,
                                            unsigned* __restrict__ Cnt,
                                            unsigned short* __restrict__ sorted)
{
    __shared__ unsigned lh[1024];
    __shared__ unsigned sBase[1024];
    int t = threadIdx.x, b = blockIdx.x;
    for (int i = t; i < 1024; i += 256) lh[i] = 0;
    __syncthreads();
    unsigned er[16];
    int base = b * 4096;
#pragma unroll
    for (int i = 0; i < 16; ++i) {
        int e = base + i * 256 + t;
        int s = ei[e], d = ei[EDGES + e];
        unsigned g = (unsigned)s >> 6;
        er[i] = (g << 12) | (unsigned)((d & 63) << 6) | (unsigned)(s & 63);
        atomicAdd(&lh[g], 1u);
    }
    __syncthreads();
    for (int i = t; i < 1024; i += 256) {
        unsigned c = lh[i];
        if (c) sBase[i] = atomicAdd(&Cnt[i], c);
    }
    __syncthreads();
    for (int i = t; i < 1024; i += 256) lh[i] = 0;
    __syncthreads();
#pragma unroll
    for (int i = 0; i < 16; ++i) {
        unsigned g = er[i] >> 12;
        unsigned r = atomicAdd(&lh[g], 1u);
        unsigned p = sBase[g] + r;
        if (p < 2048) sorted[(size_t)g * 2048 + p] = (unsigned short)(er[i] & 0xFFFu);
    }
}

// ---- prepS: S[v][j] = sum_o vemb[v][o]*aff_W2[j][o] via MFMA; batt ----
__global__ __launch_bounds__(256) void prepS(
    const float* __restrict__ vemb, const float* __restrict__ aff_b2,
    const bf* __restrict__ gW2f, bf* __restrict__ gS, float* __restrict__ gbatt)
{
    __shared__ __align__(16) bf sV[32 * VS];
    const int t = threadIdx.x, g = blockIdx.x;
    const int wv = t >> 6, lane = t & 63, l15 = lane & 15, q = lane >> 4;
    const int kofs = q * 8;
    const float4* gv = (const float4*)(vemb + (size_t)g * 4096);
#pragma unroll
    for (int tt = 0; tt < 4; ++tt) {
        int i = t + tt * 256;
        int v = i >> 5, o4 = i & 31;
        float4 w = gv[i];
        bf4 tv;
        tv.v[0] = __float2bfloat16(w.x); tv.v[1] = __float2bfloat16(w.y);
        tv.v[2] = __float2bfloat16(w.z); tv.v[3] = __float2bfloat16(w.w);
        *(bf4*)(sV + v * VS + o4 * 4) = tv;
    }
    __syncthreads();
    // batt[v] = sum_o aff_b2[o]*vemb[v][o]
    {
        int v = t >> 3, sg = t & 7;
        float s = 0.f;
        const bf* pv = sV + v * VS + sg * 16;
        const float* pb = aff_b2 + sg * 16;
#pragma unroll
        for (int o = 0; o < 16; ++o) s += pb[o] * __bfloat162float(pv[o]);
        s += __shfl_xor(s, 1); s += __shfl_xor(s, 2); s += __shfl_xor(s, 4);
        if (sg == 0) gbatt[g * 32 + v] = s;
    }
    // GEMM: wave wv -> mt = wv&1, n-tiles (wv>>1)*4 .. +3
    {
        const int mt = wv & 1, nb = (wv >> 1) * 4;
        f32x4 acc[4] = {};
#pragma unroll
        for (int ks = 0; ks < 4; ++ks) {
            short8 a = *(const short8*)(sV + (mt * 16 + l15) * VS + ks * 32 + kofs);
#pragma unroll
            for (int nt = 0; nt < 4; ++nt) {
                short8 bb = *(const short8*)(gW2f + foff(nb + nt, ks, l15, kofs));
                acc[nt] = __builtin_amdgcn_mfma_f32_16x16x32_bf16(a, bb, acc[nt], 0, 0, 0);
            }
        }
        // store into fragment-linear gS (B rows = v, k = j)
#pragma unroll
        for (int nt = 0; nt < 4; ++nt)
#pragma unroll
            for (int r = 0; r < 4; ++r) {
                int v = mt * 16 + q * 4 + r;
                int k = (nb + nt) * 16 + l15;
                int off = ((v >> 4) * 4 + (k >> 5)) * 512 + (v & 15) * 32 + (k & 31);
                gS[(size_t)g * 4096 + off] = __float2bfloat16(acc[nt][r]);
            }
    }
}

// GEMM helpers: A-frags in regs, B streamed from global fragment-linear
__device__ __forceinline__ void gemmA8(const short8 A[4], const bf* __restrict__ gW,
                                       int l15, int kofs, f32x4 acc[8])
{
#pragma unroll
    for (int hf = 0; hf < 2; ++hf) {
        short8 b[4], bn[4];
#pragma unroll
        for (int nt = 0; nt < 4; ++nt)
            b[nt] = *(const short8*)(gW + foff(hf * 4 + nt, 0, l15, kofs));
#pragma unroll
        for (int ks = 0; ks < 4; ++ks) {
            if (ks < 3)
#pragma unroll
                for (int nt = 0; nt < 4; ++nt)
                    bn[nt] = *(const short8*)(gW + foff(hf * 4 + nt, ks + 1, l15, kofs));
#pragma unroll
            for (int nt = 0; nt < 4; ++nt)
                acc[hf * 4 + nt] = __builtin_amdgcn_mfma_f32_16x16x32_bf16(
                    A[ks], b[nt], acc[hf * 4 + nt], 0, 0, 0);
#pragma unroll
            for (int nt = 0; nt < 4; ++nt) b[nt] = bn[nt];
        }
    }
}

__device__ __forceinline__ void gemmA4(const short8 A[4], const bf* __restrict__ gW,
                                       int ntb, int l15, int kofs, f32x4 acc[4])
{
    short8 b[4], bn[4];
#pragma unroll
    for (int nt = 0; nt < 4; ++nt)
        b[nt] = *(const short8*)(gW + foff(ntb + nt, 0, l15, kofs));
#pragma unroll
    for (int ks = 0; ks < 4; ++ks) {
        if (ks < 3)
#pragma unroll
            for (int nt = 0; nt < 4; ++nt)
                bn[nt] = *(const short8*)(gW + foff(ntb + nt, ks + 1, l15, kofs));
#pragma unroll
        for (int nt = 0; nt < 4; ++nt)
            acc[nt] = __builtin_amdgcn_mfma_f32_16x16x32_bf16(A[ks], b[nt], acc[nt], 0, 0, 0);
#pragma unroll
        for (int nt = 0; nt < 4; ++nt) b[nt] = bn[nt];
    }
}

// D-layout values -> A-frags of the same matrix via wave-private slab (no barrier)
__device__ __forceinline__ void bounceA(const float vals[8][4], bf* slab,
                                        int q, int l15, short8 A[4])
{
#pragma unroll
    for (int ks = 0; ks < 4; ++ks) {
#pragma unroll
        for (int h = 0; h < 2; ++h)
#pragma unroll
            for (int r = 0; r < 4; ++r)
                slab[(q * 4 + r) * BS + h * 16 + l15] = __float2bfloat16(vals[ks * 2 + h][r]);
        A[ks] = *(const short8*)(slab + l15 * BS + q * 8);
    }
}

__global__ __launch_bounds__(256, 4) void fused_graph(
    const float* __restrict__ x, const float* __restrict__ edge_w,
    const bf* __restrict__ gWb, const float* __restrict__ bfold,
    const float* __restrict__ b_gcn, const float* __restrict__ aff_b1,
    const float* __restrict__ vn_b1, const float* __restrict__ vn_b2,
    const bf* __restrict__ gS, const float* __restrict__ gbatt,
    const unsigned short* __restrict__ sorted, const unsigned* __restrict__ Cnt,
    float* __restrict__ gfout)
{
    __shared__ __align__(16) bf sT [128 * TS];        // 18,432 B: hws^T -> hgcn^T -> vn1(RM)
    __shared__ __align__(16) bf sAdj[64 * AS];        //  8,192 B: adj -> ewn^T
    __shared__ __align__(16) bf sBounce[4 * 16 * BS]; //  5,120 B: wave slabs; later sGfp
    __shared__ __align__(16) bf sVn[32 * VS];         //  8,704 B: cnt words -> vn(RM)
    __shared__ float sInv[64];                        //    256 B
    // total 40,704 B -> 4 blocks/CU (16 waves/CU), all 1024 blocks co-resident

    const int tid = threadIdx.x;
    const int g = blockIdx.x;
    const int wv = tid >> 6;
    const int lane = tid & 63;
    const int l15 = lane & 15;
    const int q = lane >> 4;
    const int kofs = q * 8;
    bf* slab = sBounce + wv * (16 * BS);
    float* sGfp = (float*)sBounce;       // alias: slabs dead after P4, sGfp used at P9
    unsigned* cnt = (unsigned*)sVn;      // alias: counts dead before P7

    // ---- B0: zero count words ----
    {
        uint4* c4 = (uint4*)cnt;
        c4[tid] = make_uint4(0, 0, 0, 0);
    }
    __syncthreads();
    // ---- P0: accumulate edge counts (LDS atomics) ----
    {
        unsigned ecnt = Cnt[g]; if (ecnt > 2048) ecnt = 2048;
        const unsigned short* seg = sorted + (size_t)g * 2048;
        for (unsigned i = tid; i < ecnt; i += 256) {
            unsigned w = seg[i];
            atomicAdd(&cnt[(w >> 6) * 16 + ((w & 63u) >> 2)], 1u << ((w & 3u) * 8));
        }
    }
    __syncthreads();
    // ---- P0c: counts -> bf16 adjacency (+self) in sAdj, inv = rsqrt(rowsum) ----
    {
        int row = tid >> 2, q4 = tid & 3;
        float rs = 0.f;
#pragma unroll
        for (int w4 = 0; w4 < 4; ++w4) {
            unsigned wd = cnt[row * 16 + q4 * 4 + w4];
            bf4 tv;
#pragma unroll
            for (int j = 0; j < 4; ++j) {
                int c = (q4 * 4 + w4) * 4 + j;
                float v = (float)((wd >> (j * 8)) & 255u) + (c == row ? 1.f : 0.f);
                rs += v;
                tv.v[j] = __float2bfloat16(v);
            }
            *(bf4*)(sAdj + row * AS + (q4 * 4 + w4) * 4) = tv;
        }
        rs += __shfl_xor(rs, 1);
        rs += __shfl_xor(rs, 2);
        if (q4 == 0) sInv[row] = rsqrtf(rs);
    }
    __syncthreads();

    // ---- P2': hw = x @ Wfold + bfold ; hws^T = inv[s]*hw -> sT ----
    {
        const float4* xrow = (const float4*)(x + ((size_t)g * 64 + 16 * wv + l15) * 128);
        short8 A[4];
#pragma unroll
        for (int ks = 0; ks < 4; ++ks) {
            float4 a0 = xrow[ks * 8 + q * 2];
            float4 a1 = xrow[ks * 8 + q * 2 + 1];
            union { short8 v; bf e[8]; } u;
            u.e[0] = __float2bfloat16(a0.x); u.e[1] = __float2bfloat16(a0.y);
            u.e[2] = __float2bfloat16(a0.z); u.e[3] = __float2bfloat16(a0.w);
            u.e[4] = __float2bfloat16(a1.x); u.e[5] = __float2bfloat16(a1.y);
            u.e[6] = __float2bfloat16(a1.z); u.e[7] = __float2bfloat16(a1.w);
            A[ks] = u.v;
        }
        f32x4 acc[8] = {};
        gemmA8(A, gWb, l15, kofs, acc);
        float bf_[8];
#pragma unroll
        for (int nt = 0; nt < 8; ++nt) bf_[nt] = bfold[nt * 16 + l15];
        float iv[4];
#pragma unroll
        for (int r = 0; r < 4; ++r) iv[r] = sInv[16 * wv + q * 4 + r];
#pragma unroll
        for (int nt = 0; nt < 8; ++nt) {
            bf4 tv;
#pragma unroll
            for (int r = 0; r < 4; ++r)
                tv.v[r] = __float2bfloat16((acc[nt][r] + bf_[nt]) * iv[r]);
            *(bf4*)(sT + (nt * 16 + l15) * TS + 16 * wv + q * 4) = tv;
        }
    }
    __syncthreads();   // B3: hws^T ready

    // ---- P3: h_gcn = relu(inv[d]*(A' @ hws) + b_gcn) ----
    float hvals[8][4];
    {
        f32x4 acc[8] = {};
#pragma unroll
        for (int ks = 0; ks < 2; ++ks) {
            short8 a = *(const short8*)(sAdj + (16 * wv + l15) * AS + ks * 32 + kofs);
#pragma unroll
            for (int nt = 0; nt < 8; ++nt) {
                short8 bb = *(const short8*)(sT + (nt * 16 + l15) * TS + ks * 32 + kofs);
                acc[nt] = __builtin_amdgcn_mfma_f32_16x16x32_bf16(a, bb, acc[nt], 0, 0, 0);
            }
        }
        float iv[4];
#pragma unroll
        for (int r = 0; r < 4; ++r) iv[r] = sInv[16 * wv + q * 4 + r];
#pragma unroll
        for (int nt = 0; nt < 8; ++nt) {
            float bg = b_gcn[nt * 16 + l15];
#pragma unroll
            for (int r = 0; r < 4; ++r)
                hvals[nt][r] = fmaxf(acc[nt][r] * iv[r] + bg, 0.f);
        }
    }
    __syncthreads();   // B4: all waves done reading hws^T / adj

    // hgcn^T -> sT (for P7); private bounce -> A-frags of h_gcn
    short8 Ah[4];
    {
#pragma unroll
        for (int nt = 0; nt < 8; ++nt) {
            bf4 tv;
#pragma unroll
            for (int r = 0; r < 4; ++r) tv.v[r] = __float2bfloat16(hvals[nt][r]);
            *(bf4*)(sT + (nt * 16 + l15) * TS + 16 * wv + q * 4) = tv;
        }
        bounceA(hvals, slab, q, l15, Ah);
    }

    // ---- P4: affh = relu(h_gcn @ aff_W1 + aff_b1)  (barrier-free) ----
    short8 Aa[4];
    {
        f32x4 acc[8] = {};
        gemmA8(Ah, gWb + 16384, l15, kofs, acc);
        float av[8][4];
#pragma unroll
        for (int nt = 0; nt < 8; ++nt) {
            float ba = aff_b1[nt * 16 + l15];
#pragma unroll
            for (int r = 0; r < 4; ++r) av[nt][r] = fmaxf(acc[nt][r] + ba, 0.f);
        }
        bounceA(av, slab, q, l15, Aa);
    }

    // ---- P6: att = affh @ S^T ; gate + row-normalize -> ewn^T (sAdj) ----
    {
        short8 Sf[8];
#pragma unroll
        for (int nt = 0; nt < 2; ++nt)
#pragma unroll
            for (int ks = 0; ks < 4; ++ks)
                Sf[nt * 4 + ks] = *(const short8*)(gS + (size_t)g * 4096 + foff(nt, ks, l15, kofs));
        float ewv[2][4];
#pragma unroll
        for (int nt = 0; nt < 2; ++nt)
#pragma unroll
            for (int r = 0; r < 4; ++r)
                ewv[nt][r] = edge_w[(size_t)g * 2048 + (16 * wv + q * 4 + r) * 32 + nt * 16 + l15];
        float bt[2] = { gbatt[g * 32 + l15], gbatt[g * 32 + 16 + l15] };
        f32x4 acc[2] = {};
#pragma unroll
        for (int ks = 0; ks < 4; ++ks) {
            acc[0] = __builtin_amdgcn_mfma_f32_16x16x32_bf16(Aa[ks], Sf[ks],     acc[0], 0, 0, 0);
            acc[1] = __builtin_amdgcn_mfma_f32_16x16x32_bf16(Aa[ks], Sf[4 + ks], acc[1], 0, 0, 0);
        }
        const float sc = 0.08838834764831845f;   // 1/sqrt(128)
        float e[2][4];
#pragma unroll
        for (int r = 0; r < 4; ++r) {
#pragma unroll
            for (int nt = 0; nt < 2; ++nt) {
                float att = (acc[nt][r] + bt[nt]) * sc;
                e[nt][r] = ewv[nt][r] * (1.f + 1.f / (1.f + __expf(-att)));
            }
            float rs = e[0][r] + e[1][r];
            rs += __shfl_xor(rs, 1); rs += __shfl_xor(rs, 2);
            rs += __shfl_xor(rs, 4); rs += __shfl_xor(rs, 8);
            float ri = (rs == 0.f) ? 1.f : 1.f / rs;
            e[0][r] *= ri; e[1][r] *= ri;
        }
#pragma unroll
        for (int nt = 0; nt < 2; ++nt) {
            bf4 tv;
#pragma unroll
            for (int r = 0; r < 4; ++r) tv.v[r] = __float2bfloat16(e[nt][r]);
            *(bf4*)(sAdj + (nt * 16 + l15) * AS + 16 * wv + q * 4) = tv;
        }
    }
    __syncthreads();   // B5: ewn^T + hgcn^T ready

    // ---- P7: vn = ewn @ h_gcn -> sVn (RM 32xVS) ----
    const int mb = wv & 1, hf = wv >> 1;
    {
        f32x4 acc[4] = {};
#pragma unroll
        for (int ks = 0; ks < 2; ++ks) {
            short8 a = *(const short8*)(sAdj + (mb * 16 + l15) * AS + ks * 32 + kofs);
#pragma unroll
            for (int nt = 0; nt < 4; ++nt) {
                short8 bb = *(const short8*)(sT + (hf * 64 + nt * 16 + l15) * TS + ks * 32 + kofs);
                acc[nt] = __builtin_amdgcn_mfma_f32_16x16x32_bf16(a, bb, acc[nt], 0, 0, 0);
            }
        }
#pragma unroll
        for (int nt = 0; nt < 4; ++nt)
#pragma unroll
            for (int r = 0; r < 4; ++r)
                sVn[(mb * 16 + q * 4 + r) * VS + hf * 64 + nt * 16 + l15] =
                    __float2bfloat16(acc[nt][r]);
    }
    __syncthreads();   // B6: vn ready (sT free)

    // ---- P8: vn1 = relu(vn @ vn_W1 + vn_b1) -> sT (RM 32xVS) ----
    bf* vn1 = sT;
    {
        short8 A[4];
#pragma unroll
        for (int ks = 0; ks < 4; ++ks)
            A[ks] = *(const short8*)(sVn + (mb * 16 + l15) * VS + ks * 32 + kofs);
        f32x4 acc[4] = {};
        gemmA4(A, gWb + 2 * 16384, hf * 4, l15, kofs, acc);
#pragma unroll
        for (int nt = 0; nt < 4; ++nt) {
            float b1 = vn_b1[hf * 64 + nt * 16 + l15];
#pragma unroll
            for (int r = 0; r < 4; ++r)
                vn1[(mb * 16 + q * 4 + r) * VS + hf * 64 + nt * 16 + l15] =
                    __float2bfloat16(fmaxf(acc[nt][r] + b1, 0.f));
        }
    }
    __syncthreads();   // B7: vn1 ready

    // ---- P9: vn2 = vn1 @ vn_W2 + vn_b2 ; partial mean over V -> sGfp ----
    {
        short8 A[4];
#pragma unroll
        for (int ks = 0; ks < 4; ++ks)
            A[ks] = *(const short8*)(vn1 + (mb * 16 + l15) * VS + ks * 32 + kofs);
        f32x4 acc[4] = {};
        gemmA4(A, gWb + 3 * 16384, hf * 4, l15, kofs, acc);
#pragma unroll
        for (int nt = 0; nt < 4; ++nt) {
            float b2 = vn_b2[hf * 64 + nt * 16 + l15];
            float p = (acc[nt][0] + b2) + (acc[nt][1] + b2) + (acc[nt][2] + b2) + (acc[nt][3] + b2);
            p += __shfl_xor(p, 16);
            p += __shfl_xor(p, 32);
            if (q == 0) sGfp[mb * 128 + hf * 64 + nt * 16 + l15] = p;
        }
    }
    __syncthreads();   // B8
    if (tid < 128)
        gfout[(size_t)g * 128 + tid] = (sGfp[tid] + sGfp[128 + tid]) * 0.03125f;
}

// ---------------- tail: out = relu(gf@W1+b1)@W2+b2 ----------------
__global__ __launch_bounds__(256) void tail_mlp(const float* __restrict__ gf,
                                                const float* __restrict__ W1,
                                                const float* __restrict__ b1,
                                                const float* __restrict__ W2,
                                                const float* __restrict__ b2,
                                                float* __restrict__ out)
{
    __shared__ float z[2][128];
    int tid = threadIdx.x;
    int half = tid >> 7, o = tid & 127;
    const float* gr = gf + (blockIdx.x * 2 + half) * 128;
    float a = b1[o];
#pragma unroll 4
    for (int k = 0; k < 128; ++k) a = fmaf(gr[k], W1[k * 128 + o], a);
    z[half][o] = fmaxf(a, 0.f);
    __syncthreads();
    if (tid < 160) {
        int grp = tid >> 3, jg = tid & 7;
        int r2 = grp / 10, oo = grp % 10;
        float p = 0.f;
#pragma unroll
        for (int t = 0; t < 16; ++t) {
            int j = jg * 16 + t;
            p = fmaf(z[r2][j], W2[j * 10 + oo], p);
        }
        p += __shfl_xor(p, 1); p += __shfl_xor(p, 2); p += __shfl_xor(p, 4);
        if (jg == 0) out[(blockIdx.x * 2 + r2) * 10 + oo] = p + b2[oo];
    }
}

extern "C" void kernel_launch(void* const* d_in, const int* in_sizes, int n_in,
                              void* d_out, int out_size, void* d_ws, size_t ws_size,
                              hipStream_t stream)
{
    const float* x       = (const float*)d_in[0];
    const int*   ei      = (const int*)  d_in[1];
    // d_in[2] = batch (unused)
    const float* edge_w  = (const float*)d_in[3];
    const float* vemb    = (const float*)d_in[4];
    const float* W_emb   = (const float*)d_in[5];
    const float* b_emb   = (const float*)d_in[6];
    const float* W_gcn   = (const float*)d_in[7];
    const float* b_gcn   = (const float*)d_in[8];
    const float* aff_W1  = (const float*)d_in[9];
    const float* aff_b1  = (const float*)d_in[10];
    const float* aff_W2  = (const float*)d_in[11];
    const float* aff_b2  = (const float*)d_in[12];
    const float* vn_W1   = (const float*)d_in[13];
    const float* vn_b1   = (const float*)d_in[14];
    const float* vn_W2   = (const float*)d_in[15];
    const float* vn_b2   = (const float*)d_in[16];
    const float* mlp_W1  = (const float*)d_in[17];
    const float* mlp_b1  = (const float*)d_in[18];
    const float* mlp_W2  = (const float*)d_in[19];
    const float* mlp_b2  = (const float*)d_in[20];

    char* ws = (char*)d_ws;
    unsigned short* sorted = (unsigned short*)ws;                      // 4 MB
    unsigned* Cnt   = (unsigned*)(ws + (4u << 20));                    // 4 KB
    bf*       gWb   = (bf*)     (ws + (4u << 20) + 65536);             // 128 KB (4 mats)
    float*    bfold = (float*)  (ws + (4u << 20) + 65536 + 131072);    // 512 B
    bf*       gW2f  = (bf*)     (ws + (4u << 20) + 262144);            // 32 KB
    bf*       gS    = (bf*)     (ws + (5u << 20));                     // 8 MB
    float*    gbatt = (float*)  (ws + (13u << 20));                    // 128 KB
    float*    gfbuf = (float*)  (ws + (14u << 20));                    // 512 KB

    conv <<<dim3(9),    dim3(256), 0, stream>>>(W_emb, W_gcn, b_emb, aff_W1,
                                                vn_W1, vn_W2, aff_W2,
                                                gWb, gW2f, bfold, Cnt);
    scat <<<dim3(256),  dim3(256), 0, stream>>>(ei, Cnt, sorted);
    prepS<<<dim3(1024), dim3(256), 0, stream>>>(vemb, aff_b2, gW2f, gS, gbatt);
    fused_graph<<<dim3(1024), dim3(256), 0, stream>>>(
        x, edge_w, gWb, bfold, b_gcn, aff_b1, vn_b1, vn_b2,
        gS, gbatt, sorted, Cnt, gfbuf);
    tail_mlp<<<dim3(512), dim3(256), 0, stream>>>(
        gfbuf, mlp_W1, mlp_b1, mlp_W2, mlp_b2, (float*)d_out);
}

// Round 6
// 213.502 us; speedup vs baseline: 1.0452x; 1.0452x over previous
//
#include <hip/hip_runtime.h>
#include <hip/hip_bf16.h>
#include <cstddef>

// G=1024 x 64 nodes, V=32, H=128, DIN=128, DOUT=10, E=1048576.
// R6 = R5 with the serial bottlenecks outside fused removed:
//  - W_emb@W_gcn fold now MFMA in ONE block of the wide `prep` kernel
//    (R5 did it scalar on 4 blocks ~35us serial).
//  - prepS folded into `prep` (blocks 0..1023), converting aff_W2 inline
//    from fp32 (no intra-kernel producer/consumer race).
//  - tail MLP merged into fused_graph (gf is block-local) -> no tail kernel.
//  - 3 dispatches total: prep, scat, fused.

#define EDGES 1048576
#define TS 72    // transposed [feat][node] stride (bf16): 144 B
#define AS 64    // adjacency / ewn^T stride: 128 B
#define VS 136   // 32-row row-major stride: 272 B
#define BS 40    // per-wave bounce slab stride: 80 B

typedef __attribute__((ext_vector_type(8))) short short8;
typedef __attribute__((ext_vector_type(4))) float f32x4;
typedef __hip_bfloat16 bf;
struct __align__(8) bf4 { bf v[4]; };

__device__ __forceinline__ int foff(int nt, int ks, int l15, int kofs) {
    return (nt * 4 + ks) * 512 + l15 * 32 + kofs;
}

__device__ __forceinline__ short8 cvt8(const float* p) {
    float4 v0 = *(const float4*)p, v1 = *(const float4*)(p + 4);
    union { short8 v; bf e[8]; } u;
    u.e[0] = __float2bfloat16(v0.x); u.e[1] = __float2bfloat16(v0.y);
    u.e[2] = __float2bfloat16(v0.z); u.e[3] = __float2bfloat16(v0.w);
    u.e[4] = __float2bfloat16(v1.x); u.e[5] = __float2bfloat16(v1.y);
    u.e[6] = __float2bfloat16(v1.z); u.e[7] = __float2bfloat16(v1.w);
    return u.v;
}

// ---- prep: blocks 0..1023 = per-graph S/batt; 1024 = fold+bfold (MFMA);
//      1025..1027 = weight transposes; 1028 = Cnt zero ----
__global__ __launch_bounds__(256) void prep(
    const float* __restrict__ vemb, const float* __restrict__ aff_b2,
    const float* __restrict__ aff_W2, const float* __restrict__ W_emb,
    const float* __restrict__ W_gcn, const float* __restrict__ b_emb,
    const float* __restrict__ aff_W1, const float* __restrict__ vn_W1,
    const float* __restrict__ vn_W2,
    bf* __restrict__ gWb, float* __restrict__ bfold,
    bf* __restrict__ gS, float* __restrict__ gbatt, unsigned* __restrict__ Cnt)
{
    const int b = blockIdx.x, t = threadIdx.x;
    const int wv = t >> 6, lane = t & 63, l15 = lane & 15, q = lane >> 4;
    const int kofs = q * 8;
    if (b < 1024) {
        // ---- S[v][j] = sum_o vemb[v][o]*aff_W2[j][o]; batt[v] ----
        __shared__ __align__(16) bf sV[32 * VS];
        const float4* gv = (const float4*)(vemb + (size_t)b * 4096);
#pragma unroll
        for (int tt = 0; tt < 4; ++tt) {
            int i = t + tt * 256;
            int v = i >> 5, o4 = i & 31;
            float4 w = gv[i];
            bf4 tv;
            tv.v[0] = __float2bfloat16(w.x); tv.v[1] = __float2bfloat16(w.y);
            tv.v[2] = __float2bfloat16(w.z); tv.v[3] = __float2bfloat16(w.w);
            *(bf4*)(sV + v * VS + o4 * 4) = tv;
        }
        __syncthreads();
        {
            int v = t >> 3, sg = t & 7;
            float s = 0.f;
            const bf* pv = sV + v * VS + sg * 16;
            const float* pb = aff_b2 + sg * 16;
#pragma unroll
            for (int o = 0; o < 16; ++o) s += pb[o] * __bfloat162float(pv[o]);
            s += __shfl_xor(s, 1); s += __shfl_xor(s, 2); s += __shfl_xor(s, 4);
            if (sg == 0) gbatt[b * 32 + v] = s;
        }
        {
            const int mt = wv & 1, nb = (wv >> 1) * 4;
            f32x4 acc[4] = {};
#pragma unroll
            for (int ks = 0; ks < 4; ++ks) {
                short8 a = *(const short8*)(sV + (mt * 16 + l15) * VS + ks * 32 + kofs);
#pragma unroll
                for (int nt = 0; nt < 4; ++nt) {
                    int n = (nb + nt) * 16 + l15;
                    short8 bb = cvt8(aff_W2 + n * 128 + ks * 32 + kofs);
                    acc[nt] = __builtin_amdgcn_mfma_f32_16x16x32_bf16(a, bb, acc[nt], 0, 0, 0);
                }
            }
#pragma unroll
            for (int nt = 0; nt < 4; ++nt)
#pragma unroll
                for (int r = 0; r < 4; ++r) {
                    int v = mt * 16 + q * 4 + r;
                    int k = (nb + nt) * 16 + l15;
                    int off = ((v >> 4) * 4 + (k >> 5)) * 512 + (v & 15) * 32 + (k & 31);
                    gS[(size_t)b * 4096 + off] = __float2bfloat16(acc[nt][r]);
                }
        }
    } else if (b == 1024) {
        // ---- bfold[j] = b_emb @ W_gcn (coalesced across j) ----
        if (t < 128) {
            float acc = 0.f;
#pragma unroll 16
            for (int m = 0; m < 128; ++m) acc = fmaf(b_emb[m], W_gcn[m * 128 + t], acc);
            bfold[t] = acc;
        }
        // ---- Wfold = W_emb @ W_gcn via MFMA; store fragment-linear gWb[0] ----
#pragma unroll
        for (int kt2 = 0; kt2 < 2; ++kt2) {
            int kt = wv * 2 + kt2;
            short8 Af[4];
#pragma unroll
            for (int ks = 0; ks < 4; ++ks)
                Af[ks] = cvt8(W_emb + (kt * 16 + l15) * 128 + ks * 32 + kofs);
#pragma unroll
            for (int jt = 0; jt < 8; ++jt) {
                f32x4 acc = {};
#pragma unroll
                for (int ks = 0; ks < 4; ++ks) {
                    union { short8 v; bf e[8]; } u;
#pragma unroll
                    for (int i = 0; i < 8; ++i)
                        u.e[i] = __float2bfloat16(W_gcn[(ks * 32 + kofs + i) * 128 + jt * 16 + l15]);
                    acc = __builtin_amdgcn_mfma_f32_16x16x32_bf16(Af[ks], u.v, acc, 0, 0, 0);
                }
#pragma unroll
                for (int r = 0; r < 4; ++r) {
                    int k = kt * 16 + q * 4 + r;
                    gWb[(jt * 4 + (k >> 5)) * 512 + l15 * 32 + (k & 31)] =
                        __float2bfloat16(acc[r]);
                }
            }
        }
    } else if (b < 1028) {
        const float* src = (b == 1025) ? aff_W1 : (b == 1026) ? vn_W1 : vn_W2;
        bf* dst = gWb + (size_t)(b - 1024) * 16384;
        for (int i = t; i < 16384; i += 256) {
            int n = i >> 7, k = i & 127;
            int off = ((n >> 4) * 4 + (k >> 5)) * 512 + (n & 15) * 32 + (k & 31);
            dst[off] = __float2bfloat16(src[k * 128 + n]);
        }
    } else {
        for (int i = t; i < 1024; i += 256) Cnt[i] = 0u;
    }
}

// ------------- scat: hist -> reserve(global atomic) -> rank+store -------------
__global__ __launch_bounds__(256) void scat(const int* __restrict__ ei,
                                            unsigned* __restrict__ Cnt,
                                            unsigned short* __restrict__ sorted)
{
    __shared__ unsigned lh[1024];
    __shared__ unsigned sBase[1024];
    int t = threadIdx.x, b = blockIdx.x;
    for (int i = t; i < 1024; i += 256) lh[i] = 0;
    __syncthreads();
    unsigned er[16];
    int base = b * 4096;
#pragma unroll
    for (int i = 0; i < 16; ++i) {
        int e = base + i * 256 + t;
        int s = ei[e], d = ei[EDGES + e];
        unsigned g = (unsigned)s >> 6;
        er[i] = (g << 12) | (unsigned)((d & 63) << 6) | (unsigned)(s & 63);
        atomicAdd(&lh[g], 1u);
    }
    __syncthreads();
    for (int i = t; i < 1024; i += 256) {
        unsigned c = lh[i];
        if (c) sBase[i] = atomicAdd(&Cnt[i], c);
    }
    __syncthreads();
    for (int i = t; i < 1024; i += 256) lh[i] = 0;
    __syncthreads();
#pragma unroll
    for (int i = 0; i < 16; ++i) {
        unsigned g = er[i] >> 12;
        unsigned r = atomicAdd(&lh[g], 1u);
        unsigned p = sBase[g] + r;
        if (p < 2048) sorted[(size_t)g * 2048 + p] = (unsigned short)(er[i] & 0xFFFu);
    }
}

// GEMM helpers: A-frags in regs, B streamed from global fragment-linear
__device__ __forceinline__ void gemmA8(const short8 A[4], const bf* __restrict__ gW,
                                       int l15, int kofs, f32x4 acc[8])
{
#pragma unroll
    for (int hf = 0; hf < 2; ++hf) {
        short8 b[4], bn[4];
#pragma unroll
        for (int nt = 0; nt < 4; ++nt)
            b[nt] = *(const short8*)(gW + foff(hf * 4 + nt, 0, l15, kofs));
#pragma unroll
        for (int ks = 0; ks < 4; ++ks) {
            if (ks < 3)
#pragma unroll
                for (int nt = 0; nt < 4; ++nt)
                    bn[nt] = *(const short8*)(gW + foff(hf * 4 + nt, ks + 1, l15, kofs));
#pragma unroll
            for (int nt = 0; nt < 4; ++nt)
                acc[hf * 4 + nt] = __builtin_amdgcn_mfma_f32_16x16x32_bf16(
                    A[ks], b[nt], acc[hf * 4 + nt], 0, 0, 0);
#pragma unroll
            for (int nt = 0; nt < 4; ++nt) b[nt] = bn[nt];
        }
    }
}

__device__ __forceinline__ void gemmA4(const short8 A[4], const bf* __restrict__ gW,
                                       int ntb, int l15, int kofs, f32x4 acc[4])
{
    short8 b[4], bn[4];
#pragma unroll
    for (int nt = 0; nt < 4; ++nt)
        b[nt] = *(const short8*)(gW + foff(ntb + nt, 0, l15, kofs));
#pragma unroll
    for (int ks = 0; ks < 4; ++ks) {
        if (ks < 3)
#pragma unroll
            for (int nt = 0; nt < 4; ++nt)
                bn[nt] = *(const short8*)(gW + foff(ntb + nt, ks + 1, l15, kofs));
#pragma unroll
        for (int nt = 0; nt < 4; ++nt)
            acc[nt] = __builtin_amdgcn_mfma_f32_16x16x32_bf16(A[ks], b[nt], acc[nt], 0, 0, 0);
#pragma unroll
        for (int nt = 0; nt < 4; ++nt) b[nt] = bn[nt];
    }
}

__device__ __forceinline__ void bounceA(const float vals[8][4], bf* slab,
                                        int q, int l15, short8 A[4])
{
#pragma unroll
    for (int ks = 0; ks < 4; ++ks) {
#pragma unroll
        for (int h = 0; h < 2; ++h)
#pragma unroll
            for (int r = 0; r < 4; ++r)
                slab[(q * 4 + r) * BS + h * 16 + l15] = __float2bfloat16(vals[ks * 2 + h][r]);
        A[ks] = *(const short8*)(slab + l15 * BS + q * 8);
    }
}

__global__ __launch_bounds__(256, 4) void fused_graph(
    const float* __restrict__ x, const float* __restrict__ edge_w,
    const bf* __restrict__ gWb, const float* __restrict__ bfold,
    const float* __restrict__ b_gcn, const float* __restrict__ aff_b1,
    const float* __restrict__ vn_b1, const float* __restrict__ vn_b2,
    const bf* __restrict__ gS, const float* __restrict__ gbatt,
    const float* __restrict__ mlp_W1, const float* __restrict__ mlp_b1,
    const float* __restrict__ mlp_W2, const float* __restrict__ mlp_b2,
    const unsigned short* __restrict__ sorted, const unsigned* __restrict__ Cnt,
    float* __restrict__ out)
{
    __shared__ __align__(16) bf sT [128 * TS];        // 18,432 B
    __shared__ __align__(16) bf sAdj[64 * AS];        //  8,192 B
    __shared__ __align__(16) bf sBounce[4 * 16 * BS]; //  5,120 B (slabs -> gf/z)
    __shared__ __align__(16) bf sVn[32 * VS];         //  8,704 B
    __shared__ float sInv[64];                        //    256 B
    // total 40,704 B -> 4 blocks/CU

    const int tid = threadIdx.x;
    const int g = blockIdx.x;
    const int wv = tid >> 6;
    const int lane = tid & 63;
    const int l15 = lane & 15;
    const int q = lane >> 4;
    const int kofs = q * 8;
    bf* slab = sBounce + wv * (16 * BS);
    float* sGfp = (float*)sBounce;       // alias after P4 (1280 floats available)
    unsigned* cnt = (unsigned*)sVn;

    {
        uint4* c4 = (uint4*)cnt;
        c4[tid] = make_uint4(0, 0, 0, 0);
    }
    __syncthreads();
    {
        unsigned ecnt = Cnt[g]; if (ecnt > 2048) ecnt = 2048;
        const unsigned short* seg = sorted + (size_t)g * 2048;
        for (unsigned i = tid; i < ecnt; i += 256) {
            unsigned w = seg[i];
            atomicAdd(&cnt[(w >> 6) * 16 + ((w & 63u) >> 2)], 1u << ((w & 3u) * 8));
        }
    }
    __syncthreads();
    {
        int row = tid >> 2, q4 = tid & 3;
        float rs = 0.f;
#pragma unroll
        for (int w4 = 0; w4 < 4; ++w4) {
            unsigned wd = cnt[row * 16 + q4 * 4 + w4];
            bf4 tv;
#pragma unroll
            for (int j = 0; j < 4; ++j) {
                int c = (q4 * 4 + w4) * 4 + j;
                float v = (float)((wd >> (j * 8)) & 255u) + (c == row ? 1.f : 0.f);
                rs += v;
                tv.v[j] = __float2bfloat16(v);
            }
            *(bf4*)(sAdj + row * AS + (q4 * 4 + w4) * 4) = tv;
        }
        rs += __shfl_xor(rs, 1);
        rs += __shfl_xor(rs, 2);
        if (q4 == 0) sInv[row] = rsqrtf(rs);
    }
    __syncthreads();

    // ---- P2': hw = x @ Wfold + bfold ; hws^T -> sT ----
    {
        const float4* xrow = (const float4*)(x + ((size_t)g * 64 + 16 * wv + l15) * 128);
        short8 A[4];
#pragma unroll
        for (int ks = 0; ks < 4; ++ks) {
            float4 a0 = xrow[ks * 8 + q * 2];
            float4 a1 = xrow[ks * 8 + q * 2 + 1];
            union { short8 v; bf e[8]; } u;
            u.e[0] = __float2bfloat16(a0.x); u.e[1] = __float2bfloat16(a0.y);
            u.e[2] = __float2bfloat16(a0.z); u.e[3] = __float2bfloat16(a0.w);
            u.e[4] = __float2bfloat16(a1.x); u.e[5] = __float2bfloat16(a1.y);
            u.e[6] = __float2bfloat16(a1.z); u.e[7] = __float2bfloat16(a1.w);
            A[ks] = u.v;
        }
        f32x4 acc[8] = {};
        gemmA8(A, gWb, l15, kofs, acc);
        float bf_[8];
#pragma unroll
        for (int nt = 0; nt < 8; ++nt) bf_[nt] = bfold[nt * 16 + l15];
        float iv[4];
#pragma unroll
        for (int r = 0; r < 4; ++r) iv[r] = sInv[16 * wv + q * 4 + r];
#pragma unroll
        for (int nt = 0; nt < 8; ++nt) {
            bf4 tv;
#pragma unroll
            for (int r = 0; r < 4; ++r)
                tv.v[r] = __float2bfloat16((acc[nt][r] + bf_[nt]) * iv[r]);
            *(bf4*)(sT + (nt * 16 + l15) * TS + 16 * wv + q * 4) = tv;
        }
    }
    __syncthreads();

    // ---- P3: h_gcn = relu(inv[d]*(A' @ hws) + b_gcn) ----
    float hvals[8][4];
    {
        f32x4 acc[8] = {};
#pragma unroll
        for (int ks = 0; ks < 2; ++ks) {
            short8 a = *(const short8*)(sAdj + (16 * wv + l15) * AS + ks * 32 + kofs);
#pragma unroll
            for (int nt = 0; nt < 8; ++nt) {
                short8 bb = *(const short8*)(sT + (nt * 16 + l15) * TS + ks * 32 + kofs);
                acc[nt] = __builtin_amdgcn_mfma_f32_16x16x32_bf16(a, bb, acc[nt], 0, 0, 0);
            }
        }
        float iv[4];
#pragma unroll
        for (int r = 0; r < 4; ++r) iv[r] = sInv[16 * wv + q * 4 + r];
#pragma unroll
        for (int nt = 0; nt < 8; ++nt) {
            float bg = b_gcn[nt * 16 + l15];
#pragma unroll
            for (int r = 0; r < 4; ++r)
                hvals[nt][r] = fmaxf(acc[nt][r] * iv[r] + bg, 0.f);
        }
    }
    __syncthreads();

    short8 Ah[4];
    {
#pragma unroll
        for (int nt = 0; nt < 8; ++nt) {
            bf4 tv;
#pragma unroll
            for (int r = 0; r < 4; ++r) tv.v[r] = __float2bfloat16(hvals[nt][r]);
            *(bf4*)(sT + (nt * 16 + l15) * TS + 16 * wv + q * 4) = tv;
        }
        bounceA(hvals, slab, q, l15, Ah);
    }

    // ---- P4: affh = relu(h_gcn @ aff_W1 + aff_b1) (barrier-free) ----
    short8 Aa[4];
    {
        f32x4 acc[8] = {};
        gemmA8(Ah, gWb + 16384, l15, kofs, acc);
        float av[8][4];
#pragma unroll
        for (int nt = 0; nt < 8; ++nt) {
            float ba = aff_b1[nt * 16 + l15];
#pragma unroll
            for (int r = 0; r < 4; ++r) av[nt][r] = fmaxf(acc[nt][r] + ba, 0.f);
        }
        bounceA(av, slab, q, l15, Aa);
    }

    // ---- P6: att = affh @ S^T ; gate + row-normalize -> ewn^T (sAdj) ----
    {
        short8 Sf[8];
#pragma unroll
        for (int nt = 0; nt < 2; ++nt)
#pragma unroll
            for (int ks = 0; ks < 4; ++ks)
                Sf[nt * 4 + ks] = *(const short8*)(gS + (size_t)g * 4096 + foff(nt, ks, l15, kofs));
        float ewv[2][4];
#pragma unroll
        for (int nt = 0; nt < 2; ++nt)
#pragma unroll
            for (int r = 0; r < 4; ++r)
                ewv[nt][r] = edge_w[(size_t)g * 2048 + (16 * wv + q * 4 + r) * 32 + nt * 16 + l15];
        float bt[2] = { gbatt[g * 32 + l15], gbatt[g * 32 + 16 + l15] };
        f32x4 acc[2] = {};
#pragma unroll
        for (int ks = 0; ks < 4; ++ks) {
            acc[0] = __builtin_amdgcn_mfma_f32_16x16x32_bf16(Aa[ks], Sf[ks],     acc[0], 0, 0, 0);
            acc[1] = __builtin_amdgcn_mfma_f32_16x16x32_bf16(Aa[ks], Sf[4 + ks], acc[1], 0, 0, 0);
        }
        const float sc = 0.08838834764831845f;
        float e[2][4];
#pragma unroll
        for (int r = 0; r < 4; ++r) {
#pragma unroll
            for (int nt = 0; nt < 2; ++nt) {
                float att = (acc[nt][r] + bt[nt]) * sc;
                e[nt][r] = ewv[nt][r] * (1.f + 1.f / (1.f + __expf(-att)));
            }
            float rs = e[0][r] + e[1][r];
            rs += __shfl_xor(rs, 1); rs += __shfl_xor(rs, 2);
            rs += __shfl_xor(rs, 4); rs += __shfl_xor(rs, 8);
            float ri = (rs == 0.f) ? 1.f : 1.f / rs;
            e[0][r] *= ri; e[1][r] *= ri;
        }
#pragma unroll
        for (int nt = 0; nt < 2; ++nt) {
            bf4 tv;
#pragma unroll
            for (int r = 0; r < 4; ++r) tv.v[r] = __float2bfloat16(e[nt][r]);
            *(bf4*)(sAdj + (nt * 16 + l15) * AS + 16 * wv + q * 4) = tv;
        }
    }
    __syncthreads();

    // ---- P7: vn = ewn @ h_gcn -> sVn ----
    const int mb = wv & 1, hf = wv >> 1;
    {
        f32x4 acc[4] = {};
#pragma unroll
        for (int ks = 0; ks < 2; ++ks) {
            short8 a = *(const short8*)(sAdj + (mb * 16 + l15) * AS + ks * 32 + kofs);
#pragma unroll
            for (int nt = 0; nt < 4; ++nt) {
                short8 bb = *(const short8*)(sT + (hf * 64 + nt * 16 + l15) * TS + ks * 32 + kofs);
                acc[nt] = __builtin_amdgcn_mfma_f32_16x16x32_bf16(a, bb, acc[nt], 0, 0, 0);
            }
        }
#pragma unroll
        for (int nt = 0; nt < 4; ++nt)
#pragma unroll
            for (int r = 0; r < 4; ++r)
                sVn[(mb * 16 + q * 4 + r) * VS + hf * 64 + nt * 16 + l15] =
                    __float2bfloat16(acc[nt][r]);
    }
    __syncthreads();

    // ---- P8: vn1 = relu(vn @ vn_W1 + vn_b1) -> sT ----
    bf* vn1 = sT;
    {
        short8 A[4];
#pragma unroll
        for (int ks = 0; ks < 4; ++ks)
            A[ks] = *(const short8*)(sVn + (mb * 16 + l15) * VS + ks * 32 + kofs);
        f32x4 acc[4] = {};
        gemmA4(A, gWb + 2 * 16384, hf * 4, l15, kofs, acc);
#pragma unroll
        for (int nt = 0; nt < 4; ++nt) {
            float b1 = vn_b1[hf * 64 + nt * 16 + l15];
#pragma unroll
            for (int r = 0; r < 4; ++r)
                vn1[(mb * 16 + q * 4 + r) * VS + hf * 64 + nt * 16 + l15] =
                    __float2bfloat16(fmaxf(acc[nt][r] + b1, 0.f));
        }
    }
    __syncthreads();

    // ---- P9: vn2 = vn1 @ vn_W2 + vn_b2 ; partial mean over V -> sGfp ----
    {
        short8 A[4];
#pragma unroll
        for (int ks = 0; ks < 4; ++ks)
            A[ks] = *(const short8*)(vn1 + (mb * 16 + l15) * VS + ks * 32 + kofs);
        f32x4 acc[4] = {};
        gemmA4(A, gWb + 3 * 16384, hf * 4, l15, kofs, acc);
#pragma unroll
        for (int nt = 0; nt < 4; ++nt) {
            float b2 = vn_b2[hf * 64 + nt * 16 + l15];
            float p = (acc[nt][0] + b2) + (acc[nt][1] + b2) + (acc[nt][2] + b2) + (acc[nt][3] + b2);
            p += __shfl_xor(p, 16);
            p += __shfl_xor(p, 32);
            if (q == 0) sGfp[mb * 128 + hf * 64 + nt * 16 + l15] = p;
        }
    }
    __syncthreads();
    // ---- P10: gf = mean over V (in place, sGfp[0..127]) ----
    if (tid < 128) sGfp[tid] = (sGfp[tid] + sGfp[128 + tid]) * 0.03125f;
    __syncthreads();
    // ---- P11: z = relu(gf @ mlp_W1 + b1) -> sGfp[128..255] ----
    if (tid < 128) {
        float a = mlp_b1[tid];
#pragma unroll 16
        for (int k = 0; k < 128; ++k) a = fmaf(sGfp[k], mlp_W1[k * 128 + tid], a);
        sGfp[128 + tid] = fmaxf(a, 0.f);
    }
    __syncthreads();
    // ---- P12: out = z @ mlp_W2 + b2 ----
    if (tid < 160) {
        int o = tid >> 4, jg = tid & 15;
        float p = 0.f;
#pragma unroll
        for (int t2 = 0; t2 < 8; ++t2) {
            int j = jg * 8 + t2;
            p = fmaf(sGfp[128 + j], mlp_W2[j * 10 + o], p);
        }
        p += __shfl_xor(p, 1); p += __shfl_xor(p, 2);
        p += __shfl_xor(p, 4); p += __shfl_xor(p, 8);
        if (jg == 0) out[g * 10 + o] = p + mlp_b2[o];
    }
}

extern "C" void kernel_launch(void* const* d_in, const int* in_sizes, int n_in,
                              void* d_out, int out_size, void* d_ws, size_t ws_size,
                              hipStream_t stream)
{
    const float* x       = (const float*)d_in[0];
    const int*   ei      = (const int*)  d_in[1];
    // d_in[2] = batch (unused)
    const float* edge_w  = (const float*)d_in[3];
    const float* vemb    = (const float*)d_in[4];
    const float* W_emb   = (const float*)d_in[5];
    const float* b_emb   = (const float*)d_in[6];
    const float* W_gcn   = (const float*)d_in[7];
    const float* b_gcn   = (const float*)d_in[8];
    const float* aff_W1  = (const float*)d_in[9];
    const float* aff_b1  = (const float*)d_in[10];
    const float* aff_W2  = (const float*)d_in[11];
    const float* aff_b2  = (const float*)d_in[12];
    const float* vn_W1   = (const float*)d_in[13];
    const float* vn_b1   = (const float*)d_in[14];
    const float* vn_W2   = (const float*)d_in[15];
    const float* vn_b2   = (const float*)d_in[16];
    const float* mlp_W1  = (const float*)d_in[17];
    const float* mlp_b1  = (const float*)d_in[18];
    const float* mlp_W2  = (const float*)d_in[19];
    const float* mlp_b2  = (const float*)d_in[20];

    char* ws = (char*)d_ws;
    unsigned short* sorted = (unsigned short*)ws;                      // 4 MB
    unsigned* Cnt   = (unsigned*)(ws + (4u << 20));                    // 4 KB
    bf*       gWb   = (bf*)     (ws + (4u << 20) + 65536);             // 128 KB
    float*    bfold = (float*)  (ws + (4u << 20) + 65536 + 131072);    // 512 B
    bf*       gS    = (bf*)     (ws + (5u << 20));                     // 8 MB
    float*    gbatt = (float*)  (ws + (13u << 20));                    // 128 KB

    prep<<<dim3(1029), dim3(256), 0, stream>>>(
        vemb, aff_b2, aff_W2, W_emb, W_gcn, b_emb, aff_W1, vn_W1, vn_W2,
        gWb, bfold, gS, gbatt, Cnt);
    scat<<<dim3(256), dim3(256), 0, stream>>>(ei, Cnt, sorted);
    fused_graph<<<dim3(1024), dim3(256), 0, stream>>>(
        x, edge_w, gWb, bfold, b_gcn, aff_b1, vn_b1, vn_b2,
        gS, gbatt, mlp_W1, mlp_b1, mlp_W2, mlp_b2, sorted, Cnt, (float*)d_out);
}

// Round 7
// 196.563 us; speedup vs baseline: 1.1352x; 1.0862x over previous
//
#include <hip/hip_runtime.h>
#include <hip/hip_bf16.h>
#include <cstddef>

// G=1024 x 64 nodes, V=32, H=128, DIN=128, DOUT=10, E=1048576.
// R7 = R6 with the aux side collapsed:
//  - S = vemb@aff_W2^T and batt computed INSIDE fused (S: 16 MFMA/wave at
//    entry into the LDS region that later holds vn; batt: scalar+shuffle).
//    prep's 1024 blocks and the 16MB gS round-trip are gone.
//  - aux = 4KB memset + ONE 261-block kernel (scat 256 + weight fold/xpose 5).
//  - entry prefetch of x-frags / vemb-frags / edge_w into VGPRs.
//  - 3 dispatches: memset, k1, fused.

#define EDGES 1048576
#define TS 72    // transposed [feat][node] stride (bf16): 144 B
#define AS 64    // adjacency / ewn^T stride: 128 B
#define SS 136   // 32-row row-major stride (S / vn): 272 B
#define BS 40    // per-wave bounce slab stride: 80 B

typedef __attribute__((ext_vector_type(8))) short short8;
typedef __attribute__((ext_vector_type(4))) float f32x4;
typedef __hip_bfloat16 bf;
struct __align__(8) bf4 { bf v[4]; };

__device__ __forceinline__ int foff(int nt, int ks, int l15, int kofs) {
    return (nt * 4 + ks) * 512 + l15 * 32 + kofs;
}

__device__ __forceinline__ short8 cvt8(const float* p) {
    float4 v0 = *(const float4*)p, v1 = *(const float4*)(p + 4);
    union { short8 v; bf e[8]; } u;
    u.e[0] = __float2bfloat16(v0.x); u.e[1] = __float2bfloat16(v0.y);
    u.e[2] = __float2bfloat16(v0.z); u.e[3] = __float2bfloat16(v0.w);
    u.e[4] = __float2bfloat16(v1.x); u.e[5] = __float2bfloat16(v1.y);
    u.e[6] = __float2bfloat16(v1.z); u.e[7] = __float2bfloat16(v1.w);
    return u.v;
}

// ---- k1: blocks 0..255 = edge scatter; 256 = Wfold+bfold; 257..259 =
//      transposed weight conversions; 260 = aff_W2 straight conversion ----
__global__ __launch_bounds__(256) void k1(
    const int* __restrict__ ei,
    const float* __restrict__ W_emb, const float* __restrict__ W_gcn,
    const float* __restrict__ b_emb, const float* __restrict__ aff_W1,
    const float* __restrict__ vn_W1, const float* __restrict__ vn_W2,
    const float* __restrict__ aff_W2,
    unsigned* __restrict__ Cnt, unsigned short* __restrict__ sorted,
    bf* __restrict__ gWb, bf* __restrict__ gW2f, float* __restrict__ bfold)
{
    const int b = blockIdx.x, t = threadIdx.x;
    if (b < 256) {
        __shared__ unsigned lh[1024];
        __shared__ unsigned sBase[1024];
        for (int i = t; i < 1024; i += 256) lh[i] = 0;
        __syncthreads();
        unsigned er[16];
        int base = b * 4096;
#pragma unroll
        for (int i = 0; i < 16; ++i) {
            int e = base + i * 256 + t;
            int s = ei[e], d = ei[EDGES + e];
            unsigned g = (unsigned)s >> 6;
            er[i] = (g << 12) | (unsigned)((d & 63) << 6) | (unsigned)(s & 63);
            atomicAdd(&lh[g], 1u);
        }
        __syncthreads();
        for (int i = t; i < 1024; i += 256) {
            unsigned c = lh[i];
            if (c) sBase[i] = atomicAdd(&Cnt[i], c);
        }
        __syncthreads();
        for (int i = t; i < 1024; i += 256) lh[i] = 0;
        __syncthreads();
#pragma unroll
        for (int i = 0; i < 16; ++i) {
            unsigned g = er[i] >> 12;
            unsigned r = atomicAdd(&lh[g], 1u);
            unsigned p = sBase[g] + r;
            if (p < 2048) sorted[(size_t)g * 2048 + p] = (unsigned short)(er[i] & 0xFFFu);
        }
    } else if (b == 256) {
        const int wv = t >> 6, lane = t & 63, l15 = lane & 15, q = lane >> 4;
        const int kofs = q * 8;
        if (t < 128) {
            float acc = 0.f;
#pragma unroll 16
            for (int m = 0; m < 128; ++m) acc = fmaf(b_emb[m], W_gcn[m * 128 + t], acc);
            bfold[t] = acc;
        }
#pragma unroll
        for (int kt2 = 0; kt2 < 2; ++kt2) {
            int kt = wv * 2 + kt2;
            short8 Af[4];
#pragma unroll
            for (int ks = 0; ks < 4; ++ks)
                Af[ks] = cvt8(W_emb + (kt * 16 + l15) * 128 + ks * 32 + kofs);
#pragma unroll
            for (int jt = 0; jt < 8; ++jt) {
                f32x4 acc = {};
#pragma unroll
                for (int ks = 0; ks < 4; ++ks) {
                    union { short8 v; bf e[8]; } u;
#pragma unroll
                    for (int i = 0; i < 8; ++i)
                        u.e[i] = __float2bfloat16(W_gcn[(ks * 32 + kofs + i) * 128 + jt * 16 + l15]);
                    acc = __builtin_amdgcn_mfma_f32_16x16x32_bf16(Af[ks], u.v, acc, 0, 0, 0);
                }
#pragma unroll
                for (int r = 0; r < 4; ++r) {
                    int k = kt * 16 + q * 4 + r;
                    gWb[(jt * 4 + (k >> 5)) * 512 + l15 * 32 + (k & 31)] =
                        __float2bfloat16(acc[r]);
                }
            }
        }
    } else if (b < 260) {
        const float* src = (b == 257) ? aff_W1 : (b == 258) ? vn_W1 : vn_W2;
        bf* dst = gWb + (size_t)(b - 256) * 16384;
        for (int i = t; i < 16384; i += 256) {
            int n = i >> 7, k = i & 127;
            int off = ((n >> 4) * 4 + (k >> 5)) * 512 + (n & 15) * 32 + (k & 31);
            dst[off] = __float2bfloat16(src[k * 128 + n]);
        }
    } else {
        for (int i = t; i < 16384; i += 256) {
            int n = i >> 7, k = i & 127;
            int off = ((n >> 4) * 4 + (k >> 5)) * 512 + (n & 15) * 32 + (k & 31);
            gW2f[off] = __float2bfloat16(aff_W2[n * 128 + k]);
        }
    }
}

// GEMM helpers: A-frags in regs, B streamed from global fragment-linear
__device__ __forceinline__ void gemmA8(const short8 A[4], const bf* __restrict__ gW,
                                       int l15, int kofs, f32x4 acc[8])
{
#pragma unroll
    for (int hf = 0; hf < 2; ++hf) {
        short8 b[4], bn[4];
#pragma unroll
        for (int nt = 0; nt < 4; ++nt)
            b[nt] = *(const short8*)(gW + foff(hf * 4 + nt, 0, l15, kofs));
#pragma unroll
        for (int ks = 0; ks < 4; ++ks) {
            if (ks < 3)
#pragma unroll
                for (int nt = 0; nt < 4; ++nt)
                    bn[nt] = *(const short8*)(gW + foff(hf * 4 + nt, ks + 1, l15, kofs));
#pragma unroll
            for (int nt = 0; nt < 4; ++nt)
                acc[hf * 4 + nt] = __builtin_amdgcn_mfma_f32_16x16x32_bf16(
                    A[ks], b[nt], acc[hf * 4 + nt], 0, 0, 0);
#pragma unroll
            for (int nt = 0; nt < 4; ++nt) b[nt] = bn[nt];
        }
    }
}

__device__ __forceinline__ void gemmA4(const short8 A[4], const bf* __restrict__ gW,
                                       int ntb, int l15, int kofs, f32x4 acc[4])
{
    short8 b[4], bn[4];
#pragma unroll
    for (int nt = 0; nt < 4; ++nt)
        b[nt] = *(const short8*)(gW + foff(ntb + nt, 0, l15, kofs));
#pragma unroll
    for (int ks = 0; ks < 4; ++ks) {
        if (ks < 3)
#pragma unroll
            for (int nt = 0; nt < 4; ++nt)
                bn[nt] = *(const short8*)(gW + foff(ntb + nt, ks + 1, l15, kofs));
#pragma unroll
        for (int nt = 0; nt < 4; ++nt)
            acc[nt] = __builtin_amdgcn_mfma_f32_16x16x32_bf16(A[ks], b[nt], acc[nt], 0, 0, 0);
#pragma unroll
        for (int nt = 0; nt < 4; ++nt) b[nt] = bn[nt];
    }
}

__device__ __forceinline__ void bounceA(const float vals[8][4], bf* slab,
                                        int q, int l15, short8 A[4])
{
#pragma unroll
    for (int ks = 0; ks < 4; ++ks) {
#pragma unroll
        for (int h = 0; h < 2; ++h)
#pragma unroll
            for (int r = 0; r < 4; ++r)
                slab[(q * 4 + r) * BS + h * 16 + l15] = __float2bfloat16(vals[ks * 2 + h][r]);
        A[ks] = *(const short8*)(slab + l15 * BS + q * 8);
    }
}

__global__ __launch_bounds__(256, 4) void fused_graph(
    const float* __restrict__ x, const float* __restrict__ edge_w,
    const float* __restrict__ vemb,
    const bf* __restrict__ gWb, const bf* __restrict__ gW2f,
    const float* __restrict__ bfold,
    const float* __restrict__ b_gcn, const float* __restrict__ aff_b1,
    const float* __restrict__ aff_b2,
    const float* __restrict__ vn_b1, const float* __restrict__ vn_b2,
    const float* __restrict__ mlp_W1, const float* __restrict__ mlp_b1,
    const float* __restrict__ mlp_W2, const float* __restrict__ mlp_b2,
    const unsigned short* __restrict__ sorted, const unsigned* __restrict__ Cnt,
    float* __restrict__ out)
{
    __shared__ __align__(16) bf sT [128 * TS];        // 18,432 B: hws^T -> hgcn^T -> vn1
    __shared__ __align__(16) bf sAdj[64 * AS];        //  8,192 B: adj -> ewn^T
    __shared__ __align__(16) bf sB  [4 * 16 * BS];    //  5,120 B: cnt -> slabs -> gf/z
    __shared__ __align__(16) bf sSV [32 * SS];        //  8,704 B: S -> vn
    __shared__ float sInv[64];                        //    256 B
    __shared__ float sBatt[32];                       //    128 B
    // total 40,832 B -> 4 blocks/CU

    const int tid = threadIdx.x;
    const int g = blockIdx.x;
    const int wv = tid >> 6;
    const int lane = tid & 63;
    const int l15 = lane & 15;
    const int q = lane >> 4;
    const int kofs = q * 8;
    const int mt = wv & 1, hf = wv >> 1;
    bf* slab = sB + wv * (16 * BS);
    float* sGfp = (float*)sB;            // alias: slabs dead after P4, writes post-B5
    unsigned* cnt = (unsigned*)sB;       // alias: dead by B2

    // ---- entry: issue global loads early ----
    unsigned ecnt = Cnt[g]; if (ecnt > 2048) ecnt = 2048;
    short8 Ax[4];
    {
        const float* xrow = x + ((size_t)g * 64 + 16 * wv + l15) * 128;
#pragma unroll
        for (int ks = 0; ks < 4; ++ks) Ax[ks] = cvt8(xrow + ks * 32 + kofs);
    }
    short8 Avm[4];
    {
        const float* vrow = vemb + (size_t)g * 4096 + (mt * 16 + l15) * 128;
#pragma unroll
        for (int ks = 0; ks < 4; ++ks) Avm[ks] = cvt8(vrow + ks * 32 + kofs);
    }
    float ewreg[2][4];
#pragma unroll
    for (int nt = 0; nt < 2; ++nt)
#pragma unroll
        for (int r = 0; r < 4; ++r)
            ewreg[nt][r] = edge_w[(size_t)g * 2048 + (16 * wv + q * 4 + r) * 32 + nt * 16 + l15];

    // ---- B0: zero cnt words ----
    ((uint4*)cnt)[tid] = make_uint4(0, 0, 0, 0);
    __syncthreads();

    // ---- P0: edge counts (LDS atomics) ----
    {
        const unsigned short* seg = sorted + (size_t)g * 2048;
        for (unsigned i = tid; i < ecnt; i += 256) {
            unsigned w = seg[i];
            atomicAdd(&cnt[(w >> 6) * 16 + ((w & 63u) >> 2)], 1u << ((w & 3u) * 8));
        }
    }
    // ---- S[v][j] = sum_o vemb[v][o]*aff_W2[j][o] -> sSV (rows v, k=j contig) ----
    {
        f32x4 accS[4] = {};
        gemmA4(Avm, gW2f, hf * 4, l15, kofs, accS);
#pragma unroll
        for (int nt = 0; nt < 4; ++nt)
#pragma unroll
            for (int r = 0; r < 4; ++r)
                sSV[(mt * 16 + q * 4 + r) * SS + (hf * 4 + nt) * 16 + l15] =
                    __float2bfloat16(accS[nt][r]);
    }
    // ---- batt[v] = aff_b2 . vemb[v] ----
    {
        int v = tid >> 3, sg = tid & 7;
        const float* pv = vemb + (size_t)g * 4096 + v * 128 + sg * 16;
        const float* pb = aff_b2 + sg * 16;
        float s = 0.f;
#pragma unroll
        for (int o = 0; o < 16; ++o) s += pb[o] * pv[o];
        s += __shfl_xor(s, 1); s += __shfl_xor(s, 2); s += __shfl_xor(s, 4);
        if (sg == 0) sBatt[v] = s;
    }
    __syncthreads();   // B1: counts complete

    // ---- P0c: counts -> bf16 adjacency (+self) in sAdj, inv = rsqrt(rowsum) ----
    {
        int row = tid >> 2, q4 = tid & 3;
        float rs = 0.f;
#pragma unroll
        for (int w4 = 0; w4 < 4; ++w4) {
            unsigned wd = cnt[row * 16 + q4 * 4 + w4];
            bf4 tv;
#pragma unroll
            for (int j = 0; j < 4; ++j) {
                int c = (q4 * 4 + w4) * 4 + j;
                float v = (float)((wd >> (j * 8)) & 255u) + (c == row ? 1.f : 0.f);
                rs += v;
                tv.v[j] = __float2bfloat16(v);
            }
            *(bf4*)(sAdj + row * AS + (q4 * 4 + w4) * 4) = tv;
        }
        rs += __shfl_xor(rs, 1);
        rs += __shfl_xor(rs, 2);
        if (q4 == 0) sInv[row] = rsqrtf(rs);
    }
    __syncthreads();   // B2

    // ---- P2': hw = x @ Wfold + bfold ; hws^T -> sT ----
    {
        f32x4 acc[8] = {};
        gemmA8(Ax, gWb, l15, kofs, acc);
        float bf_[8];
#pragma unroll
        for (int nt = 0; nt < 8; ++nt) bf_[nt] = bfold[nt * 16 + l15];
        float iv[4];
#pragma unroll
        for (int r = 0; r < 4; ++r) iv[r] = sInv[16 * wv + q * 4 + r];
#pragma unroll
        for (int nt = 0; nt < 8; ++nt) {
            bf4 tv;
#pragma unroll
            for (int r = 0; r < 4; ++r)
                tv.v[r] = __float2bfloat16((acc[nt][r] + bf_[nt]) * iv[r]);
            *(bf4*)(sT + (nt * 16 + l15) * TS + 16 * wv + q * 4) = tv;
        }
    }
    __syncthreads();   // B3: hws^T ready

    // ---- P3: h_gcn = relu(inv[d]*(A' @ hws) + b_gcn) ----
    float hvals[8][4];
    {
        f32x4 acc[8] = {};
#pragma unroll
        for (int ks = 0; ks < 2; ++ks) {
            short8 a = *(const short8*)(sAdj + (16 * wv + l15) * AS + ks * 32 + kofs);
#pragma unroll
            for (int nt = 0; nt < 8; ++nt) {
                short8 bb = *(const short8*)(sT + (nt * 16 + l15) * TS + ks * 32 + kofs);
                acc[nt] = __builtin_amdgcn_mfma_f32_16x16x32_bf16(a, bb, acc[nt], 0, 0, 0);
            }
        }
        float iv[4];
#pragma unroll
        for (int r = 0; r < 4; ++r) iv[r] = sInv[16 * wv + q * 4 + r];
#pragma unroll
        for (int nt = 0; nt < 8; ++nt) {
            float bg = b_gcn[nt * 16 + l15];
#pragma unroll
            for (int r = 0; r < 4; ++r)
                hvals[nt][r] = fmaxf(acc[nt][r] * iv[r] + bg, 0.f);
        }
    }
    __syncthreads();   // B4: all waves done reading hws^T / adj

    short8 Ah[4];
    {
#pragma unroll
        for (int nt = 0; nt < 8; ++nt) {
            bf4 tv;
#pragma unroll
            for (int r = 0; r < 4; ++r) tv.v[r] = __float2bfloat16(hvals[nt][r]);
            *(bf4*)(sT + (nt * 16 + l15) * TS + 16 * wv + q * 4) = tv;
        }
        bounceA(hvals, slab, q, l15, Ah);
    }

    // ---- P4: affh = relu(h_gcn @ aff_W1 + aff_b1) (barrier-free) ----
    short8 Aa[4];
    {
        f32x4 acc[8] = {};
        gemmA8(Ah, gWb + 16384, l15, kofs, acc);
        float av[8][4];
#pragma unroll
        for (int nt = 0; nt < 8; ++nt) {
            float ba = aff_b1[nt * 16 + l15];
#pragma unroll
            for (int r = 0; r < 4; ++r) av[nt][r] = fmaxf(acc[nt][r] + ba, 0.f);
        }
        bounceA(av, slab, q, l15, Aa);
    }

    // ---- P6: att = affh @ S^T (S from LDS); gate + row-normalize -> ewn^T ----
    {
        f32x4 acc[2] = {};
#pragma unroll
        for (int ks = 0; ks < 4; ++ks) {
            short8 s0 = *(const short8*)(sSV + l15 * SS + ks * 32 + kofs);
            short8 s1 = *(const short8*)(sSV + (16 + l15) * SS + ks * 32 + kofs);
            acc[0] = __builtin_amdgcn_mfma_f32_16x16x32_bf16(Aa[ks], s0, acc[0], 0, 0, 0);
            acc[1] = __builtin_amdgcn_mfma_f32_16x16x32_bf16(Aa[ks], s1, acc[1], 0, 0, 0);
        }
        const float sc = 0.08838834764831845f;   // 1/sqrt(128)
        float bt[2] = { sBatt[l15], sBatt[16 + l15] };
        float e[2][4];
#pragma unroll
        for (int r = 0; r < 4; ++r) {
#pragma unroll
            for (int nt = 0; nt < 2; ++nt) {
                float att = (acc[nt][r] + bt[nt]) * sc;
                e[nt][r] = ewreg[nt][r] * (1.f + 1.f / (1.f + __expf(-att)));
            }
            float rs = e[0][r] + e[1][r];
            rs += __shfl_xor(rs, 1); rs += __shfl_xor(rs, 2);
            rs += __shfl_xor(rs, 4); rs += __shfl_xor(rs, 8);
            float ri = (rs == 0.f) ? 1.f : 1.f / rs;
            e[0][r] *= ri; e[1][r] *= ri;
        }
#pragma unroll
        for (int nt = 0; nt < 2; ++nt) {
            bf4 tv;
#pragma unroll
            for (int r = 0; r < 4; ++r) tv.v[r] = __float2bfloat16(e[nt][r]);
            *(bf4*)(sAdj + (nt * 16 + l15) * AS + 16 * wv + q * 4) = tv;
        }
    }
    __syncthreads();   // B5: ewn^T + hgcn^T ready; S dead -> sSV becomes vn

    // ---- P7: vn = ewn @ h_gcn -> sSV (RM 32xSS) ----
    {
        f32x4 acc[4] = {};
#pragma unroll
        for (int ks = 0; ks < 2; ++ks) {
            short8 a = *(const short8*)(sAdj + (mt * 16 + l15) * AS + ks * 32 + kofs);
#pragma unroll
            for (int nt = 0; nt < 4; ++nt) {
                short8 bb = *(const short8*)(sT + (hf * 64 + nt * 16 + l15) * TS + ks * 32 + kofs);
                acc[nt] = __builtin_amdgcn_mfma_f32_16x16x32_bf16(a, bb, acc[nt], 0, 0, 0);
            }
        }
#pragma unroll
        for (int nt = 0; nt < 4; ++nt)
#pragma unroll
            for (int r = 0; r < 4; ++r)
                sSV[(mt * 16 + q * 4 + r) * SS + hf * 64 + nt * 16 + l15] =
                    __float2bfloat16(acc[nt][r]);
    }
    __syncthreads();   // B6: vn ready (sT free)

    // ---- P8: vn1 = relu(vn @ vn_W1 + vn_b1) -> sT ----
    bf* vn1 = sT;
    {
        short8 A[4];
#pragma unroll
        for (int ks = 0; ks < 4; ++ks)
            A[ks] = *(const short8*)(sSV + (mt * 16 + l15) * SS + ks * 32 + kofs);
        f32x4 acc[4] = {};
        gemmA4(A, gWb + 2 * 16384, hf * 4, l15, kofs, acc);
#pragma unroll
        for (int nt = 0; nt < 4; ++nt) {
            float b1 = vn_b1[hf * 64 + nt * 16 + l15];
#pragma unroll
            for (int r = 0; r < 4; ++r)
                vn1[(mt * 16 + q * 4 + r) * SS + hf * 64 + nt * 16 + l15] =
                    __float2bfloat16(fmaxf(acc[nt][r] + b1, 0.f));
        }
    }
    __syncthreads();   // B7: vn1 ready

    // ---- P9: vn2 = vn1 @ vn_W2 + vn_b2 ; partial mean over V -> sGfp ----
    {
        short8 A[4];
#pragma unroll
        for (int ks = 0; ks < 4; ++ks)
            A[ks] = *(const short8*)(vn1 + (mt * 16 + l15) * SS + ks * 32 + kofs);
        f32x4 acc[4] = {};
        gemmA4(A, gWb + 3 * 16384, hf * 4, l15, kofs, acc);
#pragma unroll
        for (int nt = 0; nt < 4; ++nt) {
            float b2 = vn_b2[hf * 64 + nt * 16 + l15];
            float p = (acc[nt][0] + b2) + (acc[nt][1] + b2) + (acc[nt][2] + b2) + (acc[nt][3] + b2);
            p += __shfl_xor(p, 16);
            p += __shfl_xor(p, 32);
            if (q == 0) sGfp[mt * 128 + hf * 64 + nt * 16 + l15] = p;
        }
    }
    __syncthreads();   // B8
    // ---- P10: gf = mean over V ----
    if (tid < 128) sGfp[tid] = (sGfp[tid] + sGfp[128 + tid]) * 0.03125f;
    __syncthreads();
    // ---- P11: z = relu(gf @ mlp_W1 + b1) ----
    if (tid < 128) {
        float a = mlp_b1[tid];
#pragma unroll 16
        for (int k = 0; k < 128; ++k) a = fmaf(sGfp[k], mlp_W1[k * 128 + tid], a);
        sGfp[128 + tid] = fmaxf(a, 0.f);
    }
    __syncthreads();
    // ---- P12: out = z @ mlp_W2 + b2 ----
    if (tid < 160) {
        int o = tid >> 4, jg = tid & 15;
        float p = 0.f;
#pragma unroll
        for (int t2 = 0; t2 < 8; ++t2) {
            int j = jg * 8 + t2;
            p = fmaf(sGfp[128 + j], mlp_W2[j * 10 + o], p);
        }
        p += __shfl_xor(p, 1); p += __shfl_xor(p, 2);
        p += __shfl_xor(p, 4); p += __shfl_xor(p, 8);
        if (jg == 0) out[g * 10 + o] = p + mlp_b2[o];
    }
}

extern "C" void kernel_launch(void* const* d_in, const int* in_sizes, int n_in,
                              void* d_out, int out_size, void* d_ws, size_t ws_size,
                              hipStream_t stream)
{
    const float* x       = (const float*)d_in[0];
    const int*   ei      = (const int*)  d_in[1];
    // d_in[2] = batch (unused)
    const float* edge_w  = (const float*)d_in[3];
    const float* vemb    = (const float*)d_in[4];
    const float* W_emb   = (const float*)d_in[5];
    const float* b_emb   = (const float*)d_in[6];
    const float* W_gcn   = (const float*)d_in[7];
    const float* b_gcn   = (const float*)d_in[8];
    const float* aff_W1  = (const float*)d_in[9];
    const float* aff_b1  = (const float*)d_in[10];
    const float* aff_W2  = (const float*)d_in[11];
    const float* aff_b2  = (const float*)d_in[12];
    const float* vn_W1   = (const float*)d_in[13];
    const float* vn_b1   = (const float*)d_in[14];
    const float* vn_W2   = (const float*)d_in[15];
    const float* vn_b2   = (const float*)d_in[16];
    const float* mlp_W1  = (const float*)d_in[17];
    const float* mlp_b1  = (const float*)d_in[18];
    const float* mlp_W2  = (const float*)d_in[19];
    const float* mlp_b2  = (const float*)d_in[20];

    char* ws = (char*)d_ws;
    unsigned short* sorted = (unsigned short*)ws;                      // 4 MB
    unsigned* Cnt   = (unsigned*)(ws + (4u << 20));                    // 4 KB
    bf*       gWb   = (bf*)     (ws + (4u << 20) + 65536);             // 128 KB
    float*    bfold = (float*)  (ws + (4u << 20) + 65536 + 131072);    // 512 B
    bf*       gW2f  = (bf*)     (ws + (4u << 20) + 262144);            // 32 KB

    hipMemsetAsync(Cnt, 0, 1024 * sizeof(unsigned), stream);
    k1<<<dim3(261), dim3(256), 0, stream>>>(
        ei, W_emb, W_gcn, b_emb, aff_W1, vn_W1, vn_W2, aff_W2,
        Cnt, sorted, gWb, gW2f, bfold);
    fused_graph<<<dim3(1024), dim3(256), 0, stream>>>(
        x, edge_w, vemb, gWb, gW2f, bfold, b_gcn, aff_b1, aff_b2,
        vn_b1, vn_b2, mlp_W1, mlp_b1, mlp_W2, mlp_b2,
        sorted, Cnt, (float*)d_out);
}